// Round 2
// baseline (393.759 us; speedup 1.0000x reference)
//
#include <hip/hip_runtime.h>
#include <hip/hip_bf16.h>
#include <cstdint>
#include <cstddef>

typedef __attribute__((ext_vector_type(8))) short bf16x8;
typedef __attribute__((ext_vector_type(4))) float f32x4;
typedef unsigned short u16;
typedef unsigned int u32;

__device__ __forceinline__ float bf2f(u16 v) {
    union { u32 u; float f; } c; c.u = ((u32)v) << 16; return c.f;
}
__device__ __forceinline__ u16 f2bf(float f) {
    union { float f; u32 u; } c; c.f = f;
    u32 u = c.u;
    return (u16)((u + 0x7FFFu + ((u >> 16) & 1u)) >> 16);  // RNE
}

#define MFMA16(a, b, c) __builtin_amdgcn_mfma_f32_16x16x32_bf16((a), (b), (c), 0, 0, 0)

union U8 { u16 h[8]; uint4 v; };

__device__ __forceinline__ U8 cvt8(float4 a, float4 b) {
    U8 u;
    u.h[0] = f2bf(a.x); u.h[1] = f2bf(a.y); u.h[2] = f2bf(a.z); u.h[3] = f2bf(a.w);
    u.h[4] = f2bf(b.x); u.h[5] = f2bf(b.y); u.h[6] = f2bf(b.z); u.h[7] = f2bf(b.w);
    return u;
}

__device__ __forceinline__ bf16x8 as_bf(uint4 v) {
    union { uint4 u; bf16x8 b; } c; c.u = v; return c.b;
}

// ---------------------------------------------------------------------------
// W transpose+cvt: Wt[n][k] bf16 = W[k][n] fp32.  64x64 LDS tiles.
// ---------------------------------------------------------------------------
struct TArgs { const float* src[4]; u16* dst[4]; };

__global__ __launch_bounds__(256)
void transpose_kernel(TArgs ta)
{
    __shared__ float T[64][65];
    const float* W = ta.src[blockIdx.z];
    u16* Wt = ta.dst[blockIdx.z];
    const int tid = threadIdx.x;
    const int bx = blockIdx.x, by = blockIdx.y;   // bx: n-tile, by: k-tile
    const int rr = tid >> 4, c4 = (tid & 15) * 4;
#pragma unroll
    for (int i = 0; i < 4; ++i) {
        int r = rr + i * 16;
        float4 v = *(const float4*)(W + (size_t)(by * 64 + r) * 1024 + bx * 64 + c4);
        T[r][c4] = v.x; T[r][c4 + 1] = v.y; T[r][c4 + 2] = v.z; T[r][c4 + 3] = v.w;
    }
    __syncthreads();
#pragma unroll
    for (int i = 0; i < 4; ++i) {
        int n = rr + i * 16;
        u16 o0 = f2bf(T[c4][n]), o1 = f2bf(T[c4 + 1][n]);
        u16 o2 = f2bf(T[c4 + 2][n]), o3 = f2bf(T[c4 + 3][n]);
        uint2 pk;
        pk.x = (u32)o0 | ((u32)o1 << 16);
        pk.y = (u32)o2 | ((u32)o3 << 16);
        *(uint2*)(Wt + (size_t)(bx * 64 + n) * 1024 + by * 64 + c4) = pk;
    }
}

// ---------------------------------------------------------------------------
// NT GEMM, 64x64 tile, BK=64, z-fused outputs.
// ---------------------------------------------------------------------------
struct GArgs {
    const u16* Bt[3];
    const float* bias[3];
    void* out[3];
    int mode[3];
};

__global__ __launch_bounds__(256, 4)
void gemm_nt_kernel(const void* __restrict__ Av, int abf, GArgs ga,
                    const float* __restrict__ resid, int M, int K,
                    int bcol0, int Nout)
{
    const int z = blockIdx.z;
    const u16* Bt = ga.Bt[z];
    const float* bias = ga.bias[z];
    void* Cout = ga.out[z];
    const int mode = ga.mode[z];

    __shared__ __align__(16) u16 As[64 * 72];
    __shared__ __align__(16) u16 Bs[64 * 72];
    const int tid = threadIdx.x;
    const int bm = blockIdx.y * 64, bn = blockIdx.x * 64;
    const int wave = tid >> 6, lane = tid & 63;
    const int quad = lane >> 4, l16 = lane & 15;
    const int wm = (wave >> 1) * 32, wn = (wave & 1) * 32;
    const int ar = tid >> 2, ac = (tid & 3) * 16;

    f32x4 acc[2][2] = {};

    for (int k0 = 0; k0 < K; k0 += 64) {
        uint4 a0v, a1v;
        if (abf) {
            const u16* A16 = (const u16*)Av + (size_t)(bm + ar) * K + k0 + ac;
            a0v = *(const uint4*)A16;
            a1v = *(const uint4*)(A16 + 8);
        } else {
            const float* ap = (const float*)Av + (size_t)(bm + ar) * K + k0 + ac;
            a0v = cvt8(*(const float4*)ap, *(const float4*)(ap + 4)).v;
            a1v = cvt8(*(const float4*)(ap + 8), *(const float4*)(ap + 12)).v;
        }
        const u16* btp = Bt + (size_t)(bcol0 + bn + ar) * K + k0 + ac;
        uint4 b0v = *(const uint4*)btp;
        uint4 b1v = *(const uint4*)(btp + 8);
        __syncthreads();
        *(uint4*)(As + ar * 72 + ac) = a0v;
        *(uint4*)(As + ar * 72 + ac + 8) = a1v;
        *(uint4*)(Bs + ar * 72 + ac) = b0v;
        *(uint4*)(Bs + ar * 72 + ac + 8) = b1v;
        __syncthreads();
#pragma unroll
        for (int kh = 0; kh < 64; kh += 32) {
            bf16x8 a0 = *(const bf16x8*)(As + (wm + l16) * 72 + kh + quad * 8);
            bf16x8 a1 = *(const bf16x8*)(As + (wm + 16 + l16) * 72 + kh + quad * 8);
            bf16x8 b0 = *(const bf16x8*)(Bs + (wn + l16) * 72 + kh + quad * 8);
            bf16x8 b1 = *(const bf16x8*)(Bs + (wn + 16 + l16) * 72 + kh + quad * 8);
            acc[0][0] = MFMA16(a0, b0, acc[0][0]);
            acc[0][1] = MFMA16(a0, b1, acc[0][1]);
            acc[1][0] = MFMA16(a1, b0, acc[1][0]);
            acc[1][1] = MFMA16(a1, b1, acc[1][1]);
        }
    }

#pragma unroll
    for (int i = 0; i < 2; ++i) {
#pragma unroll
        for (int j = 0; j < 2; ++j) {
            int col = bn + wn + j * 16 + l16;
            float bb = bias[bcol0 + col];
#pragma unroll
            for (int r = 0; r < 4; ++r) {
                int row = bm + wm + i * 16 + quad * 4 + r;
                float v = acc[i][j][r] + bb;
                if (mode == 0) {
                    ((u16*)Cout)[(size_t)row * Nout + col] = f2bf(v);
                } else if (mode == 1) {
                    ((u16*)Cout)[(size_t)col * M + row] = f2bf(v);
                } else {
                    ((float*)Cout)[(size_t)row * Nout + col] = v + resid[(size_t)row * Nout + col];
                }
            }
        }
    }
}

// ---------------------------------------------------------------------------
// Far-tile constants: cst[(hg*4+w)*2048+s]
// ---------------------------------------------------------------------------
__global__ __launch_bounds__(256)
void consts_kernel(const u16* __restrict__ Qg, const u16* __restrict__ Kg,
                   const u16* __restrict__ posKg, const u16* __restrict__ posQg,
                   float* __restrict__ cst, int ld)
{
    const int s = blockIdx.x * 256 + threadIdx.x;
    const int hg = blockIdx.y;
    float d0 = 0.f, d1 = 0.f, d2 = 0.f, d3 = 0.f;
#pragma unroll
    for (int c = 0; c < 64; c += 8) {
        U8 q, k, p0, p1, r0, r1;
        q.v  = *(const uint4*)(Qg + (size_t)s * ld + hg * 64 + c);
        k.v  = *(const uint4*)(Kg + (size_t)s * ld + hg * 64 + c);
        p0.v = *(const uint4*)(posKg + (size_t)0 * ld + hg * 64 + c);
        p1.v = *(const uint4*)(posKg + (size_t)1023 * ld + hg * 64 + c);
        r0.v = *(const uint4*)(posQg + (size_t)0 * ld + hg * 64 + c);
        r1.v = *(const uint4*)(posQg + (size_t)1023 * ld + hg * 64 + c);
#pragma unroll
        for (int j = 0; j < 8; ++j) {
            float qq = bf2f(q.h[j]), kk = bf2f(k.h[j]);
            d0 += qq * bf2f(p0.h[j]);
            d1 += qq * bf2f(p1.h[j]);
            d2 += kk * bf2f(r0.h[j]);
            d3 += kk * bf2f(r1.h[j]);
        }
    }
    cst[(size_t)(hg * 4 + 0) * 2048 + s] = d0;
    cst[(size_t)(hg * 4 + 1) * 2048 + s] = d1;
    cst[(size_t)(hg * 4 + 2) * 2048 + s] = d2;
    cst[(size_t)(hg * 4 + 3) * 2048 + s] = d3;
}

// ---------------------------------------------------------------------------
// Fused flash attention; near tiles use band MFMAs with clip, far tiles use
// precomputed row constants.  XCD-swizzled so each XCD owns 2 heads (L2-
// resident working set), pos fragments register-prefetched one tile ahead.
// ---------------------------------------------------------------------------
__global__ __launch_bounds__(256, 2)
void attn_kernel(const u16* __restrict__ Qg, const u16* __restrict__ Kg,
                 const u16* __restrict__ Vtg, const u16* __restrict__ posKg,
                 const u16* __restrict__ posQg, const float* __restrict__ cst,
                 u16* __restrict__ ctx, int h0, int ld)
{
    __shared__ __align__(16) u16 Ks[2][64 * 72];
    __shared__ __align__(16) u16 Vs[2][64 * 72];
    __shared__ __align__(16) u16 bandC[64 * 132];  // Ps aliased per-wave (stride 88)
    __shared__ __align__(16) u16 bandP[64 * 132];
    const int tid = threadIdx.x;

    // XCD-aware remap: flat id b round-robins across 8 XCDs (xcd = b&7).
    // Map so XCD c serves exactly heads {2c, 2c+1}: working set ~1.5MB << 4MB L2.
    int hg, qi;
    if (gridDim.y == 16) {
        const int b = blockIdx.x + (blockIdx.y << 5);
        const int xcd = b & 7, r = b >> 3;
        hg = (xcd << 1) | (r & 1);
        qi = r >> 1;
    } else {
        hg = blockIdx.y; qi = blockIdx.x;
    }
    const int q0 = qi * 64;
    const int wave = tid >> 6, lane = tid & 63, quad = lane >> 4, l16 = lane & 15;
    const int br0 = (wave >> 1) * 32, bc0 = (wave & 1) * 64;
    const float rscale = 0.07216878364870322f;   // 1/sqrt(192)

    bf16x8 aq0 = *(const bf16x8*)(Qg + (size_t)(q0 + wave * 16 + l16) * ld + hg * 64 + quad * 8);
    bf16x8 aq1 = *(const bf16x8*)(Qg + (size_t)(q0 + wave * 16 + l16) * ld + hg * 64 + 32 + quad * 8);
    bf16x8 aCq[2][2];
#pragma unroll
    for (int mi = 0; mi < 2; ++mi)
#pragma unroll
        for (int kh = 0; kh < 2; ++kh)
            aCq[mi][kh] = *(const bf16x8*)(Qg + (size_t)(q0 + br0 + mi * 16 + l16) * ld
                                           + hg * 64 + kh * 32 + quad * 8);

    // far-path per-row q constants
    float cq0[4] = {}, cq1[4] = {};
    if (cst) {
#pragma unroll
        for (int r = 0; r < 4; ++r) {
            int qgl = q0 + wave * 16 + quad * 4 + r;
            cq0[r] = cst[(size_t)(hg * 4 + 0) * 2048 + qgl];
            cq1[r] = cst[(size_t)(hg * 4 + 1) * 2048 + qgl];
        }
    }

    uint4 kpre[2], vpre[2];
    const int sm0 = tid >> 3, sd0 = (tid & 7) * 8;
    const int sm1 = (tid + 256) >> 3, sd1 = sd0;
    auto loadtile = [&](int kt) {
        kpre[0] = *(const uint4*)(Kg + (size_t)(kt + sm0) * ld + hg * 64 + sd0);
        vpre[0] = *(const uint4*)(Vtg + (size_t)(hg * 64 + sm0) * 2048 + kt + sd0);
        kpre[1] = *(const uint4*)(Kg + (size_t)(kt + sm1) * ld + hg * 64 + sd1);
        vpre[1] = *(const uint4*)(Vtg + (size_t)(hg * 64 + sm1) * 2048 + kt + sd1);
    };
    auto storetile = [&](int b) {
        *(uint4*)(Ks[b] + sm0 * 72 + sd0) = kpre[0];
        *(uint4*)(Vs[b] + sm0 * 72 + sd0) = vpre[0];
        *(uint4*)(Ks[b] + sm1 * 72 + sd1) = kpre[1];
        *(uint4*)(Vs[b] + sm1 * 72 + sd1) = vpre[1];
    };

    // ---- pos fragment / far-const register prefetch (one tile ahead)
    uint4 pk[8], pq[8];     // [kh*4+ni]
    float fck[4];
    const u16* posKbase = posKg + hg * 64 + quad * 8;
    const u16* posQbase = posQg + hg * 64 + quad * 8;

    auto issue_pos = [&](int ktn) {
        const int kapb = q0 - ktn + 449 + bc0 + l16;
#pragma unroll
        for (int ni = 0; ni < 4; ++ni) {
            int kap = kapb + ni * 16;
            kap = kap < 0 ? 0 : (kap > 1023 ? 1023 : kap);
            const u16* pK = posKbase + (size_t)kap * ld;
            const u16* pQ = posQbase + (size_t)kap * ld;
            pk[ni]     = *(const uint4*)pK;
            pk[4 + ni] = *(const uint4*)(pK + 32);
            pq[ni]     = *(const uint4*)pQ;
            pq[4 + ni] = *(const uint4*)(pQ + 32);
        }
    };
    auto issue_cst = [&](int ktn, int dn) {
        const float* pc = cst + (size_t)(hg * 4 + (dn > 0 ? 2 : 3)) * 2048 + ktn + l16;
#pragma unroll
        for (int j = 0; j < 4; ++j) fck[j] = pc[j * 16];
    };

    loadtile(0); storetile(0);
    loadtile(64);
    {   // prologue prefetch for tile 0 (diff = -q0, far iff q0 >= 576)
        const bool far0 = cst && (q0 >= 576);
        if (far0) issue_cst(0, -q0); else issue_pos(0);
    }
    __syncthreads();

    f32x4 O[4] = {};
    float lrun[4] = {0.f, 0.f, 0.f, 0.f};

    for (int kt = 0, cur = 0; kt < 2048; kt += 64, cur ^= 1) {
        const int diff = kt - q0;
        const bool far = cst && (diff >= 576 || diff <= -576);

        if (!far) {
            f32x4 accC[2][4] = {}, accP[2][4] = {};
            bf16x8 aP[2][2];
#pragma unroll
            for (int kh = 0; kh < 2; ++kh)
#pragma unroll
                for (int mi = 0; mi < 2; ++mi)
                    aP[kh][mi] = *(const bf16x8*)(Ks[cur] + (br0 + mi * 16 + l16) * 72 + kh * 32 + quad * 8);
#pragma unroll
            for (int kh = 0; kh < 2; ++kh)
#pragma unroll
                for (int ni = 0; ni < 4; ++ni) {
                    bf16x8 bK = as_bf(pk[kh * 4 + ni]);
                    bf16x8 bQ = as_bf(pq[kh * 4 + ni]);
#pragma unroll
                    for (int mi = 0; mi < 2; ++mi) {
                        accC[mi][ni] = MFMA16(aCq[mi][kh], bK, accC[mi][ni]);
                        accP[mi][ni] = MFMA16(aP[kh][mi], bQ, accP[mi][ni]);
                    }
                }
#pragma unroll
            for (int mi = 0; mi < 2; ++mi)
#pragma unroll
                for (int ni = 0; ni < 4; ++ni)
#pragma unroll
                    for (int r = 0; r < 4; ++r) {
                        int row = br0 + mi * 16 + quad * 4 + r;
                        int col = bc0 + ni * 16 + l16;
                        bandC[row * 132 + col] = f2bf(accC[mi][ni][r]);
                        bandP[row * 132 + col] = f2bf(accP[mi][ni][r]);
                    }
        }

        // ---- S = Q K^T (before the band barrier: hides it)
        f32x4 s[4];
#pragma unroll
        for (int j = 0; j < 4; ++j) {
            f32x4 z = {0.f, 0.f, 0.f, 0.f};
            bf16x8 b0 = *(const bf16x8*)(Ks[cur] + (j * 16 + l16) * 72 + quad * 8);
            bf16x8 b1 = *(const bf16x8*)(Ks[cur] + (j * 16 + l16) * 72 + 32 + quad * 8);
            z = MFMA16(aq0, b0, z);
            z = MFMA16(aq1, b1, z);
            s[j] = z;
        }

        // ---- far: fold constants now (consumes fck before its reissue)
        float pj[4][4];
        if (far) {
            const float* cq = (diff > 0) ? cq0 : cq1;
#pragma unroll
            for (int j = 0; j < 4; ++j)
#pragma unroll
                for (int r = 0; r < 4; ++r)
                    pj[j][r] = s[j][r] + cq[r] + fck[j];
        }

        // ---- prefetch next tile's pos fragments / far consts
        {
            int ktn = kt + 64;
            if (ktn < 2048) {
                int dn = ktn - q0;
                bool farn = cst && (dn >= 576 || dn <= -576);
                if (farn) issue_cst(ktn, dn); else issue_pos(ktn);
            }
        }

        // ---- logits + exp
        if (far) {
#pragma unroll
            for (int j = 0; j < 4; ++j)
#pragma unroll
                for (int r = 0; r < 4; ++r) {
                    float l = pj[j][r] * rscale;
                    float e = exp2f(fminf(l, 60.f) * 1.44269504f);
                    pj[j][r] = e;
                    lrun[r] += e;
                }
        } else {
            __syncthreads();   // bands visible
#pragma unroll
            for (int j = 0; j < 4; ++j) {
                int kl = j * 16 + l16;
#pragma unroll
                for (int r = 0; r < 4; ++r) {
                    int ql = wave * 16 + quad * 4 + r;
                    int col = ql - kl + 63;
                    float l = (s[j][r] + bf2f(bandC[ql * 132 + col])
                                       + bf2f(bandP[kl * 132 + col])) * rscale;
                    float e = exp2f(fminf(l, 60.f) * 1.44269504f);
                    pj[j][r] = e;
                    lrun[r] += e;
                }
            }
        }

        // ---- P into wave-private aliased region of bandC
        u16* Pw = bandC + wave * 2112;
#pragma unroll
        for (int j = 0; j < 4; ++j)
#pragma unroll
            for (int r = 0; r < 4; ++r)
                Pw[(quad * 4 + r) * 88 + j * 16 + l16] = f2bf(pj[j][r]);

        if (kt + 64 < 2048) storetile(cur ^ 1);
        if (kt + 128 < 2048) loadtile(kt + 128);

        // ---- PV
        bf16x8 ap0 = *(const bf16x8*)(Pw + l16 * 88 + quad * 8);
        bf16x8 ap1 = *(const bf16x8*)(Pw + l16 * 88 + 32 + quad * 8);
#pragma unroll
        for (int jd = 0; jd < 4; ++jd) {
            bf16x8 v0 = *(const bf16x8*)(Vs[cur] + (jd * 16 + l16) * 72 + quad * 8);
            bf16x8 v1 = *(const bf16x8*)(Vs[cur] + (jd * 16 + l16) * 72 + 32 + quad * 8);
            O[jd] = MFMA16(ap0, v0, O[jd]);
            O[jd] = MFMA16(ap1, v1, O[jd]);
        }
        __syncthreads();
    }

#pragma unroll
    for (int m = 1; m < 16; m <<= 1)
#pragma unroll
        for (int r = 0; r < 4; ++r)
            lrun[r] += __shfl_xor(lrun[r], m, 64);

#pragma unroll
    for (int jd = 0; jd < 4; ++jd)
#pragma unroll
        for (int r = 0; r < 4; ++r) {
            int row = q0 + wave * 16 + quad * 4 + r;
            int col = (h0 + hg) * 64 + jd * 16 + l16;
            float inv = 1.0f / fmaxf(lrun[r], 1e-20f);
            ctx[(size_t)row * 1024 + col] = f2bf(O[jd][r] * inv);
        }
}

// ---------------------------------------------------------------------------
// Row LayerNorm: x (fp32, ws) -> d_out (fp32)
// ---------------------------------------------------------------------------
__global__ __launch_bounds__(256, 4)
void ln_kernel(const float* __restrict__ x, const float* __restrict__ g,
               const float* __restrict__ b, float* __restrict__ out)
{
    const int row = blockIdx.x;
    const int tid = threadIdx.x;
    const int wave = tid >> 6, lane = tid & 63;
    const float* xr = x + (size_t)row * 1024;
    float v[4]; float s = 0.f;
#pragma unroll
    for (int i = 0; i < 4; ++i) { v[i] = xr[tid + i * 256]; s += v[i]; }
    __shared__ float red[4];
    __shared__ float red2[4];
#pragma unroll
    for (int m = 1; m < 64; m <<= 1) s += __shfl_xor(s, m, 64);
    if (lane == 0) red[wave] = s;
    __syncthreads();
    float mu = (red[0] + red[1] + red[2] + red[3]) * (1.f / 1024.f);
    float vs = 0.f;
#pragma unroll
    for (int i = 0; i < 4; ++i) { float d = v[i] - mu; vs += d * d; }
#pragma unroll
    for (int m = 1; m < 64; m <<= 1) vs += __shfl_xor(vs, m, 64);
    if (lane == 0) red2[wave] = vs;
    __syncthreads();
    float var = (red2[0] + red2[1] + red2[2] + red2[3]) * (1.f / 1024.f);
    float rstd = rsqrtf(var + 1e-5f);
#pragma unroll
    for (int i = 0; i < 4; ++i) {
        int c = tid + i * 256;
        out[(size_t)row * 1024 + c] = (v[i] - mu) * rstd * g[c] + b[c];
    }
}

// ---------------------------------------------------------------------------
extern "C" void kernel_launch(void* const* d_in, const int* in_sizes, int n_in,
                              void* d_out, int out_size, void* d_ws, size_t ws_size,
                              hipStream_t stream)
{
    const float* hs  = (const float*)d_in[0];
    // d_in[1] = attention_mask (all ones) -- unused
    const float* rel = (const float*)d_in[2];
    const float* Wq  = (const float*)d_in[3];
    const float* bq  = (const float*)d_in[4];
    const float* Wk  = (const float*)d_in[5];
    const float* bk  = (const float*)d_in[6];
    const float* Wv  = (const float*)d_in[7];
    const float* bv  = (const float*)d_in[8];
    const float* Wo  = (const float*)d_in[9];
    const float* bo  = (const float*)d_in[10];
    const float* lng = (const float*)d_in[11];
    const float* lnb = (const float*)d_in[12];

    u16* Wqt = (u16*)d_out;
    u16* Wkt = Wqt + (size_t)1024 * 1024;
    u16* Wvt = Wkt + (size_t)1024 * 1024;
    u16* Wot = Wvt + (size_t)1024 * 1024;
    float* cst = (float*)d_out;          // 16*4*2048 floats = 512 KB

    const size_t MB = 1024 * 1024;
    size_t fixed = 256 + 4 * MB + 4096;
    int G = 1;
    if (ws_size > fixed + MB) {
        size_t g = (ws_size - fixed) / MB;
        G = g > 16 ? 16 : (int)g;
    }
    if (G < 1) G = 1;

    char* w = (char*)d_ws;
    size_t off = 0;
    auto take = [&](size_t n) { void* p = w + off; off = (off + n + 255) & ~(size_t)255; return p; };
    (void)take(256);
    u16* ctx = (u16*)take((size_t)2048 * 1024 * 2);
    float* xalt = nullptr;
    if (G < 8) {
        size_t budget = (ws_size > fixed + 8 * MB) ? (ws_size - fixed - 8 * MB) / MB : 1;
        G = budget < 1 ? 1 : (budget > 16 ? 16 : (int)budget);
        xalt = (float*)take((size_t)2048 * 1024 * 4);
    }
    u16* Qg    = (u16*)take((size_t)2048 * 64 * G * 2);
    u16* Kg    = (u16*)take((size_t)2048 * 64 * G * 2);
    u16* Vtg   = (u16*)take((size_t)64 * G * 2048 * 2);
    u16* posKg = (u16*)take((size_t)1024 * 64 * G * 2);
    u16* posQg = (u16*)take((size_t)1024 * 64 * G * 2);
    float* x = xalt ? xalt : (float*)Qg;

    dim3 blk(256);

    TArgs ta;
    ta.src[0] = Wq; ta.src[1] = Wk; ta.src[2] = Wv; ta.src[3] = Wo;
    ta.dst[0] = Wqt; ta.dst[1] = Wkt; ta.dst[2] = Wvt; ta.dst[3] = Wot;
    transpose_kernel<<<dim3(16, 16, 4), blk, 0, stream>>>(ta);

    const bool full = (G == 16);
    for (int h0 = 0; h0 < 16; h0 += G) {
        int gcnt = (16 - h0) < G ? (16 - h0) : G;
        int Ng = 64 * gcnt, bc0 = 64 * h0;

        GArgs qa;
        qa.Bt[0] = Wqt; qa.bias[0] = bq; qa.out[0] = Qg;  qa.mode[0] = 0;
        qa.Bt[1] = Wkt; qa.bias[1] = bk; qa.out[1] = Kg;  qa.mode[1] = 0;
        qa.Bt[2] = Wvt; qa.bias[2] = bv; qa.out[2] = Vtg; qa.mode[2] = 1;
        gemm_nt_kernel<<<dim3(gcnt, 32, 3), blk, 0, stream>>>(hs, 0, qa, nullptr, 2048, 1024, bc0, Ng);

        GArgs pa;
        pa.Bt[0] = Wkt; pa.bias[0] = bk; pa.out[0] = posKg; pa.mode[0] = 0;
        pa.Bt[1] = Wqt; pa.bias[1] = bq; pa.out[1] = posQg; pa.mode[1] = 0;
        pa.Bt[2] = Wqt; pa.bias[2] = bq; pa.out[2] = posQg; pa.mode[2] = 0;  // unused z
        gemm_nt_kernel<<<dim3(gcnt, 16, 2), blk, 0, stream>>>(rel, 0, pa, nullptr, 1024, 1024, bc0, Ng);

        if (full)
            consts_kernel<<<dim3(8, G), blk, 0, stream>>>(Qg, Kg, posKg, posQg, cst, Ng);

        attn_kernel<<<dim3(32, gcnt), blk, 0, stream>>>(Qg, Kg, Vtg, posKg, posQg,
                                                        full ? cst : nullptr, ctx, h0, Ng);
    }

    GArgs fa;
    fa.Bt[0] = Wot; fa.bias[0] = bo; fa.out[0] = x; fa.mode[0] = 2;
    fa.Bt[1] = Wot; fa.bias[1] = bo; fa.out[1] = x; fa.mode[1] = 2;
    fa.Bt[2] = Wot; fa.bias[2] = bo; fa.out[2] = x; fa.mode[2] = 2;
    gemm_nt_kernel<<<dim3(16, 32, 1), blk, 0, stream>>>(ctx, 1, fa, hs, 2048, 1024, 0, 1024);

    ln_kernel<<<dim3(2048), blk, 0, stream>>>(x, lng, lnb, (float*)d_out);
}

// Round 3
// 351.577 us; speedup vs baseline: 1.1200x; 1.1200x over previous
//
#include <hip/hip_runtime.h>
#include <hip/hip_bf16.h>
#include <cstdint>
#include <cstddef>

typedef __attribute__((ext_vector_type(8))) short bf16x8;
typedef __attribute__((ext_vector_type(4))) float f32x4;
typedef unsigned short u16;
typedef unsigned int u32;

__device__ __forceinline__ float bf2f(u16 v) {
    union { u32 u; float f; } c; c.u = ((u32)v) << 16; return c.f;
}
__device__ __forceinline__ u16 f2bf(float f) {
    union { float f; u32 u; } c; c.f = f;
    u32 u = c.u;
    return (u16)((u + 0x7FFFu + ((u >> 16) & 1u)) >> 16);  // RNE
}

#define MFMA16(a, b, c) __builtin_amdgcn_mfma_f32_16x16x32_bf16((a), (b), (c), 0, 0, 0)

union U8 { u16 h[8]; uint4 v; };

__device__ __forceinline__ U8 cvt8(float4 a, float4 b) {
    U8 u;
    u.h[0] = f2bf(a.x); u.h[1] = f2bf(a.y); u.h[2] = f2bf(a.z); u.h[3] = f2bf(a.w);
    u.h[4] = f2bf(b.x); u.h[5] = f2bf(b.y); u.h[6] = f2bf(b.z); u.h[7] = f2bf(b.w);
    return u;
}

// ---------------------------------------------------------------------------
// W transpose+cvt: Wt[n][k] bf16 = W[k][n] fp32.  64x64 LDS tiles.
// ---------------------------------------------------------------------------
struct TArgs { const float* src[4]; u16* dst[4]; };

__global__ __launch_bounds__(256)
void transpose_kernel(TArgs ta)
{
    __shared__ float T[64][65];
    const float* W = ta.src[blockIdx.z];
    u16* Wt = ta.dst[blockIdx.z];
    const int tid = threadIdx.x;
    const int bx = blockIdx.x, by = blockIdx.y;   // bx: n-tile, by: k-tile
    const int rr = tid >> 4, c4 = (tid & 15) * 4;
#pragma unroll
    for (int i = 0; i < 4; ++i) {
        int r = rr + i * 16;
        float4 v = *(const float4*)(W + (size_t)(by * 64 + r) * 1024 + bx * 64 + c4);
        T[r][c4] = v.x; T[r][c4 + 1] = v.y; T[r][c4 + 2] = v.z; T[r][c4 + 3] = v.w;
    }
    __syncthreads();
#pragma unroll
    for (int i = 0; i < 4; ++i) {
        int n = rr + i * 16;
        u16 o0 = f2bf(T[c4][n]), o1 = f2bf(T[c4 + 1][n]);
        u16 o2 = f2bf(T[c4 + 2][n]), o3 = f2bf(T[c4 + 3][n]);
        uint2 pk;
        pk.x = (u32)o0 | ((u32)o1 << 16);
        pk.y = (u32)o2 | ((u32)o3 << 16);
        *(uint2*)(Wt + (size_t)(bx * 64 + n) * 1024 + by * 64 + c4) = pk;
    }
}

// ---------------------------------------------------------------------------
// NT GEMM, 64x64 tile, BK=64, z-fused outputs.
// ---------------------------------------------------------------------------
struct GArgs {
    const u16* Bt[3];
    const float* bias[3];
    void* out[3];
    int mode[3];
};

__global__ __launch_bounds__(256, 4)
void gemm_nt_kernel(const void* __restrict__ Av, int abf, GArgs ga,
                    const float* __restrict__ resid, int M, int K,
                    int bcol0, int Nout)
{
    const int z = blockIdx.z;
    const u16* Bt = ga.Bt[z];
    const float* bias = ga.bias[z];
    void* Cout = ga.out[z];
    const int mode = ga.mode[z];

    __shared__ __align__(16) u16 As[64 * 72];
    __shared__ __align__(16) u16 Bs[64 * 72];
    const int tid = threadIdx.x;
    const int bm = blockIdx.y * 64, bn = blockIdx.x * 64;
    const int wave = tid >> 6, lane = tid & 63;
    const int quad = lane >> 4, l16 = lane & 15;
    const int wm = (wave >> 1) * 32, wn = (wave & 1) * 32;
    const int ar = tid >> 2, ac = (tid & 3) * 16;

    f32x4 acc[2][2] = {};

    for (int k0 = 0; k0 < K; k0 += 64) {
        uint4 a0v, a1v;
        if (abf) {
            const u16* A16 = (const u16*)Av + (size_t)(bm + ar) * K + k0 + ac;
            a0v = *(const uint4*)A16;
            a1v = *(const uint4*)(A16 + 8);
        } else {
            const float* ap = (const float*)Av + (size_t)(bm + ar) * K + k0 + ac;
            a0v = cvt8(*(const float4*)ap, *(const float4*)(ap + 4)).v;
            a1v = cvt8(*(const float4*)(ap + 8), *(const float4*)(ap + 12)).v;
        }
        const u16* btp = Bt + (size_t)(bcol0 + bn + ar) * K + k0 + ac;
        uint4 b0v = *(const uint4*)btp;
        uint4 b1v = *(const uint4*)(btp + 8);
        __syncthreads();
        *(uint4*)(As + ar * 72 + ac) = a0v;
        *(uint4*)(As + ar * 72 + ac + 8) = a1v;
        *(uint4*)(Bs + ar * 72 + ac) = b0v;
        *(uint4*)(Bs + ar * 72 + ac + 8) = b1v;
        __syncthreads();
#pragma unroll
        for (int kh = 0; kh < 64; kh += 32) {
            bf16x8 a0 = *(const bf16x8*)(As + (wm + l16) * 72 + kh + quad * 8);
            bf16x8 a1 = *(const bf16x8*)(As + (wm + 16 + l16) * 72 + kh + quad * 8);
            bf16x8 b0 = *(const bf16x8*)(Bs + (wn + l16) * 72 + kh + quad * 8);
            bf16x8 b1 = *(const bf16x8*)(Bs + (wn + 16 + l16) * 72 + kh + quad * 8);
            acc[0][0] = MFMA16(a0, b0, acc[0][0]);
            acc[0][1] = MFMA16(a0, b1, acc[0][1]);
            acc[1][0] = MFMA16(a1, b0, acc[1][0]);
            acc[1][1] = MFMA16(a1, b1, acc[1][1]);
        }
    }

#pragma unroll
    for (int i = 0; i < 2; ++i) {
#pragma unroll
        for (int j = 0; j < 2; ++j) {
            int col = bn + wn + j * 16 + l16;
            float bb = bias[bcol0 + col];
#pragma unroll
            for (int r = 0; r < 4; ++r) {
                int row = bm + wm + i * 16 + quad * 4 + r;
                float v = acc[i][j][r] + bb;
                if (mode == 0) {
                    ((u16*)Cout)[(size_t)row * Nout + col] = f2bf(v);
                } else if (mode == 1) {
                    ((u16*)Cout)[(size_t)col * M + row] = f2bf(v);
                } else {
                    ((float*)Cout)[(size_t)row * Nout + col] = v + resid[(size_t)row * Nout + col];
                }
            }
        }
    }
}

// ---------------------------------------------------------------------------
// Far-tile constants: cst[(hg*4+w)*2048+s]
// ---------------------------------------------------------------------------
__global__ __launch_bounds__(256)
void consts_kernel(const u16* __restrict__ Qg, const u16* __restrict__ Kg,
                   const u16* __restrict__ posKg, const u16* __restrict__ posQg,
                   float* __restrict__ cst, int ld)
{
    const int s = blockIdx.x * 256 + threadIdx.x;
    const int hg = blockIdx.y;
    float d0 = 0.f, d1 = 0.f, d2 = 0.f, d3 = 0.f;
#pragma unroll
    for (int c = 0; c < 64; c += 8) {
        U8 q, k, p0, p1, r0, r1;
        q.v  = *(const uint4*)(Qg + (size_t)s * ld + hg * 64 + c);
        k.v  = *(const uint4*)(Kg + (size_t)s * ld + hg * 64 + c);
        p0.v = *(const uint4*)(posKg + (size_t)0 * ld + hg * 64 + c);
        p1.v = *(const uint4*)(posKg + (size_t)1023 * ld + hg * 64 + c);
        r0.v = *(const uint4*)(posQg + (size_t)0 * ld + hg * 64 + c);
        r1.v = *(const uint4*)(posQg + (size_t)1023 * ld + hg * 64 + c);
#pragma unroll
        for (int j = 0; j < 8; ++j) {
            float qq = bf2f(q.h[j]), kk = bf2f(k.h[j]);
            d0 += qq * bf2f(p0.h[j]);
            d1 += qq * bf2f(p1.h[j]);
            d2 += kk * bf2f(r0.h[j]);
            d3 += kk * bf2f(r1.h[j]);
        }
    }
    cst[(size_t)(hg * 4 + 0) * 2048 + s] = d0;
    cst[(size_t)(hg * 4 + 1) * 2048 + s] = d1;
    cst[(size_t)(hg * 4 + 2) * 2048 + s] = d2;
    cst[(size_t)(hg * 4 + 3) * 2048 + s] = d3;
}

// ---------------------------------------------------------------------------
// Fused flash attention.  Parallelogram bands (each wave computes only the
// 16x80 diagonal strip it consumes), single-buffered K/V tiles (register
// prefetch carries the next tile), XCD-swizzled heads.
// LDS = 9216*2 + 11264*2 = 40960 B -> 3-4 blocks/CU (was 2).
// ---------------------------------------------------------------------------
__global__ __launch_bounds__(256, 3)
void attn_kernel(const u16* __restrict__ Qg, const u16* __restrict__ Kg,
                 const u16* __restrict__ Vtg, const u16* __restrict__ posKg,
                 const u16* __restrict__ posQg, const float* __restrict__ cst,
                 u16* __restrict__ ctx, int h0, int ld)
{
    __shared__ __align__(16) u16 Ks[64 * 72];
    __shared__ __align__(16) u16 Vs[64 * 72];
    // per-wave 16 rows x 80 cols (stride 88, 16B-aligned rows); P aliases bandC
    __shared__ __align__(16) u16 bandC[4 * 16 * 88];
    __shared__ __align__(16) u16 bandP[4 * 16 * 88];
    const int tid = threadIdx.x;

    // XCD-aware remap: flat id round-robins across 8 XCDs (xcd = b&7).
    // XCD c serves exactly heads {2c, 2c+1}: working set ~1.5MB << 4MB L2.
    int hg, qi;
    if (gridDim.y == 16) {
        const int b = blockIdx.x + (blockIdx.y << 5);
        const int xcd = b & 7, r = b >> 3;
        hg = (xcd << 1) | (r & 1);
        qi = r >> 1;
    } else {
        hg = blockIdx.y; qi = blockIdx.x;
    }
    const int q0 = qi * 64;
    const int wave = tid >> 6, lane = tid & 63, quad = lane >> 4, l16 = lane & 15;
    const float rscale = 0.07216878364870322f;   // 1/sqrt(192)

    // Q rows wave*16+l16 (A-operand for S and for c2p band MFMAs)
    bf16x8 aq0 = *(const bf16x8*)(Qg + (size_t)(q0 + wave * 16 + l16) * ld + hg * 64 + quad * 8);
    bf16x8 aq1 = *(const bf16x8*)(Qg + (size_t)(q0 + wave * 16 + l16) * ld + hg * 64 + 32 + quad * 8);

    // far-path per-row q constants
    float cq0[4] = {}, cq1[4] = {};
    if (cst) {
#pragma unroll
        for (int r = 0; r < 4; ++r) {
            int qgl = q0 + wave * 16 + quad * 4 + r;
            cq0[r] = cst[(size_t)(hg * 4 + 0) * 2048 + qgl];
            cq1[r] = cst[(size_t)(hg * 4 + 1) * 2048 + qgl];
        }
    }

    uint4 kpre[2], vpre[2];
    const int sm0 = tid >> 3, sd0 = (tid & 7) * 8;
    const int sm1 = (tid + 256) >> 3, sd1 = sd0;
    auto loadtile = [&](int kt) {
        kpre[0] = *(const uint4*)(Kg + (size_t)(kt + sm0) * ld + hg * 64 + sd0);
        vpre[0] = *(const uint4*)(Vtg + (size_t)(hg * 64 + sm0) * 2048 + kt + sd0);
        kpre[1] = *(const uint4*)(Kg + (size_t)(kt + sm1) * ld + hg * 64 + sd1);
        vpre[1] = *(const uint4*)(Vtg + (size_t)(hg * 64 + sm1) * 2048 + kt + sd1);
    };
    auto storetile = [&]() {
        *(uint4*)(Ks + sm0 * 72 + sd0) = kpre[0];
        *(uint4*)(Vs + sm0 * 72 + sd0) = vpre[0];
        *(uint4*)(Ks + sm1 * 72 + sd1) = kpre[1];
        *(uint4*)(Vs + sm1 * 72 + sd1) = vpre[1];
    };

    loadtile(0); storetile();
    loadtile(64);
    __syncthreads();

    f32x4 O[4] = {};
    float lrun[4] = {0.f, 0.f, 0.f, 0.f};

    for (int kt = 0; kt < 2048; kt += 64) {
        const int diff = kt - q0;
        const bool far = cst && (diff >= 576 || diff <= -576);

        if (!far) {
            // ---- parallelogram band: wave w computes rows [w16,w16+16) of
            // c2p (q-rows) and p2c (k-rows), 5 col-tiles of 16 each.
            const int kappa0 = q0 - kt + 449;
            bf16x8 aP0 = *(const bf16x8*)(Ks + (wave * 16 + l16) * 72 + quad * 8);
            bf16x8 aP1 = *(const bf16x8*)(Ks + (wave * 16 + l16) * 72 + 32 + quad * 8);
            const int baseC = kappa0 + wave * 16 + l16;
            const int baseP = kappa0 + 48 - wave * 16 + l16;
            u16* bCw = bandC + wave * 1408;
            u16* bPw = bandP + wave * 1408;
#pragma unroll
            for (int n = 0; n < 5; ++n) {
                int kc = baseC + n * 16; kc = kc < 0 ? 0 : (kc > 1023 ? 1023 : kc);
                int kp = baseP + n * 16; kp = kp < 0 ? 0 : (kp > 1023 ? 1023 : kp);
                const u16* pK = posKg + (size_t)kc * ld + hg * 64;
                const u16* pQ = posQg + (size_t)kp * ld + hg * 64;
                bf16x8 bK0 = *(const bf16x8*)(pK + quad * 8);
                bf16x8 bK1 = *(const bf16x8*)(pK + 32 + quad * 8);
                bf16x8 bQ0 = *(const bf16x8*)(pQ + quad * 8);
                bf16x8 bQ1 = *(const bf16x8*)(pQ + 32 + quad * 8);
                f32x4 aC = {0.f, 0.f, 0.f, 0.f}, aPv = {0.f, 0.f, 0.f, 0.f};
                aC = MFMA16(aq0, bK0, aC);
                aC = MFMA16(aq1, bK1, aC);
                aPv = MFMA16(aP0, bQ0, aPv);
                aPv = MFMA16(aP1, bQ1, aPv);
#pragma unroll
                for (int r = 0; r < 4; ++r) {
                    bCw[(quad * 4 + r) * 88 + n * 16 + l16] = f2bf(aC[r]);
                    bPw[(quad * 4 + r) * 88 + n * 16 + l16] = f2bf(aPv[r]);
                }
            }
            __syncthreads();   // A: bands visible
        }

        // ---- S = Q K^T
        f32x4 s[4];
#pragma unroll
        for (int j = 0; j < 4; ++j) {
            f32x4 z = {0.f, 0.f, 0.f, 0.f};
            bf16x8 b0 = *(const bf16x8*)(Ks + (j * 16 + l16) * 72 + quad * 8);
            bf16x8 b1 = *(const bf16x8*)(Ks + (j * 16 + l16) * 72 + 32 + quad * 8);
            z = MFMA16(aq0, b0, z);
            z = MFMA16(aq1, b1, z);
            s[j] = z;
        }

        // ---- logits + exp
        float pj[4][4];
        if (far) {
            const float* pc = cst + (size_t)(hg * 4 + (diff > 0 ? 2 : 3)) * 2048 + kt;
            const float* cq = (diff > 0) ? cq0 : cq1;
            float ck[4];
#pragma unroll
            for (int j = 0; j < 4; ++j) ck[j] = pc[j * 16 + l16];
#pragma unroll
            for (int j = 0; j < 4; ++j)
#pragma unroll
                for (int r = 0; r < 4; ++r) {
                    float l = (s[j][r] + cq[r] + ck[j]) * rscale;
                    float e = exp2f(fminf(l, 60.f) * 1.44269504f);
                    pj[j][r] = e;
                    lrun[r] += e;
                }
        } else {
            // c2p: bandC[wave][ql15][ql15-kl+63]; p2c: bandP[kl>>4][kl&15][ql-(kl&15)+15]
            const int bC0 = wave * 1408 + 63 - l16;     // + ql15*89 - j*16
            const int bP0 = l16 * 87 + wave * 16 + 15;  // + j*1408 + ql15
#pragma unroll
            for (int j = 0; j < 4; ++j)
#pragma unroll
                for (int r = 0; r < 4; ++r) {
                    int ql15 = quad * 4 + r;
                    float c2p = bf2f(bandC[bC0 + ql15 * 89 - j * 16]);
                    float p2c = bf2f(bandP[bP0 + j * 1408 + ql15]);
                    float l = (s[j][r] + c2p + p2c) * rscale;
                    float e = exp2f(fminf(l, 60.f) * 1.44269504f);
                    pj[j][r] = e;
                    lrun[r] += e;
                }
        }

        // ---- P into wave-private region (aliases bandC rows this wave owns)
        u16* Pw = bandC + wave * 1408;
#pragma unroll
        for (int j = 0; j < 4; ++j)
#pragma unroll
            for (int r = 0; r < 4; ++r)
                Pw[(quad * 4 + r) * 88 + j * 16 + l16] = f2bf(pj[j][r]);

        // ---- PV
        bf16x8 ap0 = *(const bf16x8*)(Pw + l16 * 88 + quad * 8);
        bf16x8 ap1 = *(const bf16x8*)(Pw + l16 * 88 + 32 + quad * 8);
#pragma unroll
        for (int jd = 0; jd < 4; ++jd) {
            bf16x8 v0 = *(const bf16x8*)(Vs + (jd * 16 + l16) * 72 + quad * 8);
            bf16x8 v1 = *(const bf16x8*)(Vs + (jd * 16 + l16) * 72 + 32 + quad * 8);
            O[jd] = MFMA16(ap0, v0, O[jd]);
            O[jd] = MFMA16(ap1, v1, O[jd]);
        }

        __syncthreads();       // B: all reads of Ks/Vs/bands done
        if (kt + 64 < 2048) {
            storetile();       // K/V <- tile t+1 (regs loaded last iter)
            if (kt + 128 < 2048) loadtile(kt + 128);
            __syncthreads();   // C: new K/V visible
        }
    }

#pragma unroll
    for (int m = 1; m < 16; m <<= 1)
#pragma unroll
        for (int r = 0; r < 4; ++r)
            lrun[r] += __shfl_xor(lrun[r], m, 64);

#pragma unroll
    for (int jd = 0; jd < 4; ++jd)
#pragma unroll
        for (int r = 0; r < 4; ++r) {
            int row = q0 + wave * 16 + quad * 4 + r;
            int col = (h0 + hg) * 64 + jd * 16 + l16;
            float inv = 1.0f / fmaxf(lrun[r], 1e-20f);
            ctx[(size_t)row * 1024 + col] = f2bf(O[jd][r] * inv);
        }
}

// ---------------------------------------------------------------------------
// Row LayerNorm: x (fp32, ws) -> d_out (fp32)
// ---------------------------------------------------------------------------
__global__ __launch_bounds__(256, 4)
void ln_kernel(const float* __restrict__ x, const float* __restrict__ g,
               const float* __restrict__ b, float* __restrict__ out)
{
    const int row = blockIdx.x;
    const int tid = threadIdx.x;
    const int wave = tid >> 6, lane = tid & 63;
    const float* xr = x + (size_t)row * 1024;
    float v[4]; float s = 0.f;
#pragma unroll
    for (int i = 0; i < 4; ++i) { v[i] = xr[tid + i * 256]; s += v[i]; }
    __shared__ float red[4];
    __shared__ float red2[4];
#pragma unroll
    for (int m = 1; m < 64; m <<= 1) s += __shfl_xor(s, m, 64);
    if (lane == 0) red[wave] = s;
    __syncthreads();
    float mu = (red[0] + red[1] + red[2] + red[3]) * (1.f / 1024.f);
    float vs = 0.f;
#pragma unroll
    for (int i = 0; i < 4; ++i) { float d = v[i] - mu; vs += d * d; }
#pragma unroll
    for (int m = 1; m < 64; m <<= 1) vs += __shfl_xor(vs, m, 64);
    if (lane == 0) red2[wave] = vs;
    __syncthreads();
    float var = (red2[0] + red2[1] + red2[2] + red2[3]) * (1.f / 1024.f);
    float rstd = rsqrtf(var + 1e-5f);
#pragma unroll
    for (int i = 0; i < 4; ++i) {
        int c = tid + i * 256;
        out[(size_t)row * 1024 + c] = (v[i] - mu) * rstd * g[c] + b[c];
    }
}

// ---------------------------------------------------------------------------
extern "C" void kernel_launch(void* const* d_in, const int* in_sizes, int n_in,
                              void* d_out, int out_size, void* d_ws, size_t ws_size,
                              hipStream_t stream)
{
    const float* hs  = (const float*)d_in[0];
    // d_in[1] = attention_mask (all ones) -- unused
    const float* rel = (const float*)d_in[2];
    const float* Wq  = (const float*)d_in[3];
    const float* bq  = (const float*)d_in[4];
    const float* Wk  = (const float*)d_in[5];
    const float* bk  = (const float*)d_in[6];
    const float* Wv  = (const float*)d_in[7];
    const float* bv  = (const float*)d_in[8];
    const float* Wo  = (const float*)d_in[9];
    const float* bo  = (const float*)d_in[10];
    const float* lng = (const float*)d_in[11];
    const float* lnb = (const float*)d_in[12];

    u16* Wqt = (u16*)d_out;
    u16* Wkt = Wqt + (size_t)1024 * 1024;
    u16* Wvt = Wkt + (size_t)1024 * 1024;
    u16* Wot = Wvt + (size_t)1024 * 1024;
    float* cst = (float*)d_out;          // 16*4*2048 floats = 512 KB

    const size_t MB = 1024 * 1024;
    size_t fixed = 256 + 4 * MB + 4096;
    int G = 1;
    if (ws_size > fixed + MB) {
        size_t g = (ws_size - fixed) / MB;
        G = g > 16 ? 16 : (int)g;
    }
    if (G < 1) G = 1;

    char* w = (char*)d_ws;
    size_t off = 0;
    auto take = [&](size_t n) { void* p = w + off; off = (off + n + 255) & ~(size_t)255; return p; };
    (void)take(256);
    u16* ctx = (u16*)take((size_t)2048 * 1024 * 2);
    float* xalt = nullptr;
    if (G < 8) {
        size_t budget = (ws_size > fixed + 8 * MB) ? (ws_size - fixed - 8 * MB) / MB : 1;
        G = budget < 1 ? 1 : (budget > 16 ? 16 : (int)budget);
        xalt = (float*)take((size_t)2048 * 1024 * 4);
    }
    u16* Qg    = (u16*)take((size_t)2048 * 64 * G * 2);
    u16* Kg    = (u16*)take((size_t)2048 * 64 * G * 2);
    u16* Vtg   = (u16*)take((size_t)64 * G * 2048 * 2);
    u16* posKg = (u16*)take((size_t)1024 * 64 * G * 2);
    u16* posQg = (u16*)take((size_t)1024 * 64 * G * 2);
    float* x = xalt ? xalt : (float*)Qg;

    dim3 blk(256);

    TArgs ta;
    ta.src[0] = Wq; ta.src[1] = Wk; ta.src[2] = Wv; ta.src[3] = Wo;
    ta.dst[0] = Wqt; ta.dst[1] = Wkt; ta.dst[2] = Wvt; ta.dst[3] = Wot;
    transpose_kernel<<<dim3(16, 16, 4), blk, 0, stream>>>(ta);

    const bool full = (G == 16);
    for (int h0 = 0; h0 < 16; h0 += G) {
        int gcnt = (16 - h0) < G ? (16 - h0) : G;
        int Ng = 64 * gcnt, bc0 = 64 * h0;

        GArgs qa;
        qa.Bt[0] = Wqt; qa.bias[0] = bq; qa.out[0] = Qg;  qa.mode[0] = 0;
        qa.Bt[1] = Wkt; qa.bias[1] = bk; qa.out[1] = Kg;  qa.mode[1] = 0;
        qa.Bt[2] = Wvt; qa.bias[2] = bv; qa.out[2] = Vtg; qa.mode[2] = 1;
        gemm_nt_kernel<<<dim3(gcnt, 32, 3), blk, 0, stream>>>(hs, 0, qa, nullptr, 2048, 1024, bc0, Ng);

        GArgs pa;
        pa.Bt[0] = Wkt; pa.bias[0] = bk; pa.out[0] = posKg; pa.mode[0] = 0;
        pa.Bt[1] = Wqt; pa.bias[1] = bq; pa.out[1] = posQg; pa.mode[1] = 0;
        pa.Bt[2] = Wqt; pa.bias[2] = bq; pa.out[2] = posQg; pa.mode[2] = 0;  // unused z
        gemm_nt_kernel<<<dim3(gcnt, 16, 2), blk, 0, stream>>>(rel, 0, pa, nullptr, 1024, 1024, bc0, Ng);

        if (full)
            consts_kernel<<<dim3(8, G), blk, 0, stream>>>(Qg, Kg, posKg, posQg, cst, Ng);

        attn_kernel<<<dim3(32, gcnt), blk, 0, stream>>>(Qg, Kg, Vtg, posKg, posQg,
                                                        full ? cst : nullptr, ctx, h0, Ng);
    }

    GArgs fa;
    fa.Bt[0] = Wot; fa.bias[0] = bo; fa.out[0] = x; fa.mode[0] = 2;
    fa.Bt[1] = Wot; fa.bias[1] = bo; fa.out[1] = x; fa.mode[1] = 2;
    fa.Bt[2] = Wot; fa.bias[2] = bo; fa.out[2] = x; fa.mode[2] = 2;
    gemm_nt_kernel<<<dim3(16, 32, 1), blk, 0, stream>>>(ctx, 1, fa, hs, 2048, 1024, 0, 1024);

    ln_kernel<<<dim3(2048), blk, 0, stream>>>(x, lng, lnb, (float*)d_out);
}